// Round 1
// baseline (4451.804 us; speedup 1.0000x reference)
//
#include <hip/hip_runtime.h>

// TGSR: y_t = y_{t-1} + M (x_t - y_{t-1}),  M = inv(L+I), via on-device Newton
// inverse + persistent cooperative scan kernel with f16 MFMA.

#define NITER 14

typedef _Float16 f16x8 __attribute__((ext_vector_type(8)));
typedef _Float16 f16x4 __attribute__((ext_vector_type(4)));
typedef float    f32x4 __attribute__((ext_vector_type(4)));

#define LDSROW 520  // 512 + 8 f16 pad (16B-aligned rows, breaks pow2 bank stride)

__launch_bounds__(256, 1)
__global__ void tgsr_kernel(const float* __restrict__ xs, const float* __restrict__ A,
                            float* __restrict__ out, unsigned char* __restrict__ wsb)
{
    // workspace layout
    unsigned* bar  = (unsigned*)wsb;
    _Float16* Bhi  = (_Float16*)(wsb + 256);     // f16 hi of B = (D+1)I - A, row-major
    _Float16* Blo  = Bhi  + 262144;              // f16 lo of B
    float*    X    = (float*)(Blo + 262144);     // fp32 master of X ~= M
    _Float16* Xrm0 = (_Float16*)(X + 262144);    // f16(256*X), row-major, ping
    _Float16* Xrm1 = Xrm0 + 262144;              // pong
    _Float16* Xhcm = Xrm1 + 262144;              // f16 hi(256*X), col-major [c][k]
    _Float16* Xlcm = Xhcm + 262144;              // f16 lo(256*X), col-major
    _Float16* Ecm  = Xlcm + 262144;              // f16(32*E), col-major
    _Float16* Zbuf0= Ecm  + 262144;              // z = x - y, f16 col-major, dbuf
    _Float16* Zbuf1= Zbuf0 + 262144;

    const int tid  = threadIdx.x;
    const int lane = tid & 63;
    const int w    = tid >> 6;     // wave 0..3
    const int q    = lane >> 4;    // quad 0..3
    const int nI   = lane & 15;
    const int bx   = blockIdx.x;
    const int jt   = bx & 7;            // col tile (== batch index)
    const int R    = (bx >> 3) * 16;    // row base (16-row tile)
    const int c    = jt * 64 + w * 16 + nI;  // this lane's output column
    const int f    = c & 63;            // feature index within batch

    __shared__ _Float16 ldsP[3][16 * LDSROW];  // 3 row-panel slots (~50 KB)
    __shared__ float red[4];

    unsigned bar_t = 0;

    auto gbar = [&]() {
        bar_t += 256;
        __syncthreads();
        if (tid == 0) {
            __threadfence();  // release: push our writes device-visible
            __hip_atomic_fetch_add(bar, 1u, __ATOMIC_RELEASE, __HIP_MEMORY_SCOPE_AGENT);
            while (__hip_atomic_load(bar, __ATOMIC_RELAXED, __HIP_MEMORY_SCOPE_AGENT) < bar_t)
                __builtin_amdgcn_s_sleep(1);
            __threadfence();  // acquire: invalidate stale caches
        }
        __syncthreads();
    };

    // stage a 16x512 f16 row-panel (rows R..R+15 of a row-major 512x512) into LDS
    auto stage = [&](int slot, const _Float16* src) {
        __syncthreads();
        #pragma unroll
        for (int rep = 0; rep < 4; ++rep) {
            int idx = tid + rep * 256;          // 0..1023 = 16 rows * 64 segs
            int row = idx >> 6, seg = idx & 63;
            *(f16x8*)&ldsP[slot][row * LDSROW + seg * 8] =
                *(const f16x8*)&src[(size_t)(R + row) * 512 + seg * 8];
        }
        __syncthreads();
    };

    // acc += Panel(LDS,slot)[16x512] @ Right_cm[:, c-cols]  (K=512, 16 MFMAs)
    auto gpass = [&](int slot, const _Float16* rcm, f32x4& acc) {
        const _Float16* zc = rcm + (size_t)c * 512;
        #pragma unroll
        for (int kk = 0; kk < 16; ++kk) {
            f16x8 a = *(const f16x8*)&ldsP[slot][nI * LDSROW + kk * 32 + q * 8];
            f16x8 b = *(const f16x8*)&zc[kk * 32 + q * 8];
            acc = __builtin_amdgcn_mfma_f32_16x16x32_f16(a, b, acc, 0, 0, 0);
        }
    };

    // ---------------- setup: D = rowsum(A); B = (D+1)I - A; X0 = diag(1/Bii) ----
    float Dr[2];
    for (int rr = 0; rr < 2; ++rr) {
        int r = bx * 2 + rr;
        float p = A[(size_t)r * 512 + tid] + A[(size_t)r * 512 + tid + 256];
        #pragma unroll
        for (int off = 32; off >= 1; off >>= 1) p += __shfl_xor(p, off, 64);
        if (lane == 0) red[w] = p;
        __syncthreads();
        Dr[rr] = red[0] + red[1] + red[2] + red[3];
        __syncthreads();
    }
    for (int rr = 0; rr < 2; ++rr) {
        int r = bx * 2 + rr;
        float dr = Dr[rr];
        for (int cc = tid; cc < 512; cc += 256) {
            float v = ((cc == r) ? (dr + 1.0f) : 0.0f) - A[(size_t)r * 512 + cc];
            _Float16 hi = (_Float16)v;
            _Float16 lo = (_Float16)(v - (float)hi);
            Bhi[(size_t)r * 512 + cc] = hi;
            Blo[(size_t)r * 512 + cc] = lo;
        }
        float dinv = 1.0f / (dr + 1.0f - A[(size_t)r * 512 + r]);
        float s  = dinv * 256.0f;     // all f16 X arrays carry 256*X (denorm-safe)
        _Float16 shi = (_Float16)s;
        _Float16 slo = (_Float16)(s - (float)shi);
        for (int cc = tid; cc < 512; cc += 256) {
            bool dg = (cc == r);
            X   [(size_t)r * 512 + cc] = dg ? dinv : 0.0f;
            Xrm0[(size_t)r * 512 + cc] = dg ? shi : (_Float16)0.0f;
            Xhcm[(size_t)r * 512 + cc] = dg ? shi : (_Float16)0.0f;  // col r == row r
            Xlcm[(size_t)r * 512 + cc] = dg ? slo : (_Float16)0.0f;
        }
    }
    gbar();

    stage(0, Bhi);   // B panels are constant: stage once
    stage(1, Blo);

    // ---------------- Newton: X <- X + X(I - B X) ----------------
    for (int nit = 0; nit < NITER; ++nit) {
        const _Float16* Xrm_cur = (nit & 1) ? Xrm1 : Xrm0;
        _Float16*       Xrm_nxt = (nit & 1) ? Xrm0 : Xrm1;

        // E = I - B@X : 3-product split-f16 (drop Blo@Xlo). acc = 256*(B@X)
        f32x4 acc = {0.f, 0.f, 0.f, 0.f};
        gpass(0, Xhcm, acc);
        gpass(0, Xlcm, acc);
        gpass(1, Xhcm, acc);
        f16x4 ev;
        #pragma unroll
        for (int r4 = 0; r4 < 4; ++r4) {
            int row = R + q * 4 + r4;
            float e = ((row == c) ? 1.0f : 0.0f) - acc[r4] * (1.0f / 256.0f);
            ev[r4] = (_Float16)(e * 32.0f);            // store 32*E
        }
        *(f16x4*)&Ecm[(size_t)c * 512 + R + q * 4] = ev;
        gbar();

        // dX = X@E ; acc2 = (256X)@(32E) = 8192*(X@E)
        stage(2, Xrm_cur);
        f32x4 acc2 = {0.f, 0.f, 0.f, 0.f};
        gpass(2, Ecm, acc2);
        f32x4 xn; f16x4 h4, l4;
        #pragma unroll
        for (int r4 = 0; r4 < 4; ++r4) {
            int row = R + q * 4 + r4;
            float xv = X[(size_t)row * 512 + c] + acc2[r4] * (1.0f / 8192.0f);
            xn[r4] = xv;
            float s = xv * 256.0f;
            h4[r4] = (_Float16)s;
            l4[r4] = (_Float16)(s - (float)(h4[r4]));
        }
        #pragma unroll
        for (int r4 = 0; r4 < 4; ++r4) {
            int row = R + q * 4 + r4;
            X[(size_t)row * 512 + c]       = xn[r4];
            Xrm_nxt[(size_t)row * 512 + c] = h4[r4];
        }
        *(f16x4*)&Xhcm[(size_t)c * 512 + R + q * 4] = h4;
        *(f16x4*)&Xlcm[(size_t)c * 512 + R + q * 4] = l4;
        gbar();
    }

    // ---------------- main scan: 128 steps, 1 barrier/step ----------------
    stage(2, (NITER & 1) ? Xrm1 : Xrm0);   // M panel resident in LDS for all steps

    f32x4 Y = {0.f, 0.f, 0.f, 0.f};
    {   // Z_0 = x_0 (Y starts at 0), col-major f16
        f16x4 zv;
        #pragma unroll
        for (int r4 = 0; r4 < 4; ++r4) {
            int row = R + q * 4 + r4;
            zv[r4] = (_Float16)xs[(((size_t)jt * 128 + 0) * 512 + row) * 64 + f];
        }
        *(f16x4*)&Zbuf0[(size_t)c * 512 + R + q * 4] = zv;
    }
    gbar();

    for (int t = 0; t < 128; ++t) {
        f32x4 acc = {0.f, 0.f, 0.f, 0.f};
        gpass(2, (t & 1) ? Zbuf1 : Zbuf0, acc);   // acc = (256M)@z
        const size_t obase = (((size_t)jt * 128 + t) * 512) * 64 + f;
        #pragma unroll
        for (int r4 = 0; r4 < 4; ++r4) {
            Y[r4] += acc[r4] * (1.0f / 256.0f);
            out[obase + (size_t)(R + q * 4 + r4) * 64] = Y[r4];
        }
        if (t < 127) {
            // produce Z_{t+1} = x_{t+1} - Y for the (rows,cols) this block owns
            const size_t xbase = (((size_t)jt * 128 + t + 1) * 512) * 64 + f;
            f16x4 zv;
            #pragma unroll
            for (int r4 = 0; r4 < 4; ++r4) {
                float xv = xs[xbase + (size_t)(R + q * 4 + r4) * 64];
                zv[r4] = (_Float16)(xv - Y[r4]);
            }
            _Float16* Zn = (t & 1) ? Zbuf0 : Zbuf1;
            *(f16x4*)&Zn[(size_t)c * 512 + R + q * 4] = zv;
            gbar();
        }
    }
}

extern "C" void kernel_launch(void* const* d_in, const int* in_sizes, int n_in,
                              void* d_out, int out_size, void* d_ws, size_t ws_size,
                              hipStream_t stream)
{
    const float* xs = (const float*)d_in[0];   // [8,128,512,64] fp32
    const float* A  = (const float*)d_in[1];   // [1,512,512] fp32
    float* out = (float*)d_out;                // [8,128,512,64] fp32
    unsigned char* ws = (unsigned char*)d_ws;  // needs ~5.6 MB

    // zero the grid-barrier counter (ws is poisoned 0xAA before every launch)
    hipMemsetAsync(d_ws, 0, 256, stream);

    void* args[] = { (void*)&xs, (void*)&A, (void*)&out, (void*)&ws };
    hipLaunchCooperativeKernel((void*)tgsr_kernel, dim3(256), dim3(256), args, 0, stream);
}

// Round 2
// 1458.000 us; speedup vs baseline: 3.0534x; 3.0534x over previous
//
#include <hip/hip_runtime.h>

// TGSR: y_t = y_{t-1} + M (x_t - y_{t-1}),  M = inv(L+I).
// Kernel A (cooperative): Newton inverse, flag-based barriers + sc1 atomics
//                         (no cache-wide flush ops).
// Kernel B (plain):       128-step scan, barrier-free — each block owns a
//                         16-column group and all 512 rows; Z in LDS; M
//                         partially pinned in VGPRs.

#define NITER 12
#define NPRE  9     // split-precision (3-product) E only for nit >= NPRE

typedef _Float16 f16x8 __attribute__((ext_vector_type(8)));
typedef _Float16 f16x4 __attribute__((ext_vector_type(4)));
typedef float    f32x4 __attribute__((ext_vector_type(4)));
typedef unsigned long long u64;

#define LDSROW 520  // 512 + 8 f16 pad

__device__ __forceinline__ u64 ald8(const void* p) {
    return __hip_atomic_load((const u64*)p, __ATOMIC_RELAXED, __HIP_MEMORY_SCOPE_AGENT);
}
__device__ __forceinline__ void ast8(void* p, u64 v) {
    __hip_atomic_store((u64*)p, v, __ATOMIC_RELAXED, __HIP_MEMORY_SCOPE_AGENT);
}
__device__ __forceinline__ void ast4(void* p, unsigned v) {
    __hip_atomic_store((unsigned*)p, v, __ATOMIC_RELAXED, __HIP_MEMORY_SCOPE_AGENT);
}
__device__ __forceinline__ f16x8 ald16(const void* p) {
    union { u64 u[2]; f16x8 v; } t;
    t.u[0] = ald8(p);
    t.u[1] = ald8((const u64*)p + 1);
    return t.v;
}
__device__ __forceinline__ u64 pack4(f16x4 v) {
    union { f16x4 v; u64 u; } t; t.v = v; return t.u;
}

// ---------------------------------------------------------------------------
// Kernel A: Newton iteration X <- X + X(I - B X), B = (D+1)I - A.
// 256 blocks x 256 threads (cooperative). All cross-block data via relaxed
// agent atomics (write-through to L3); barrier = per-block flag + poll.
// ---------------------------------------------------------------------------
__launch_bounds__(256, 1)
__global__ void newton_kernel(const float* __restrict__ A, unsigned char* __restrict__ wsb)
{
    unsigned* flags = (unsigned*)wsb;                 // 256 flags, 64 B apart
    _Float16* Xrm0 = (_Float16*)(wsb + 16384);        // f16(256*X), row-major (ping)  == final M
    _Float16* Xrm1 = Xrm0 + 262144;                   // pong
    _Float16* Xhcm = Xrm1 + 262144;                   // f16 hi(256*X), col-major [c][k]
    _Float16* Xlcm = Xhcm + 262144;                   // f16 lo(256*X), col-major
    _Float16* Ecm  = Xlcm + 262144;                   // f16(32*E), col-major

    const int tid  = threadIdx.x;
    const int lane = tid & 63;
    const int w    = tid >> 6;
    const int q    = lane >> 4;
    const int nI   = lane & 15;
    const int bx   = blockIdx.x;
    const int jt   = bx & 7;
    const int R    = (bx >> 3) * 16;
    const int c    = jt * 64 + w * 16 + nI;

    __shared__ _Float16 ldsP[3][16 * LDSROW];   // slot0 Bhi, slot1 Blo, slot2 staging
    __shared__ float drs[16], dinvs[16];

    unsigned bt = 0;
    auto fbar = [&]() {
        ++bt;
        __syncthreads();                         // waits vmcnt per wave (workgroup release)
        if (tid == 0)
            __hip_atomic_store(&flags[bx * 16], bt, __ATOMIC_RELAXED, __HIP_MEMORY_SCOPE_AGENT);
        while (__hip_atomic_load(&flags[tid * 16], __ATOMIC_RELAXED, __HIP_MEMORY_SCOPE_AGENT) < bt)
            __builtin_amdgcn_s_sleep(2);
        __syncthreads();
    };

    // stage rows R..R+15 of a row-major matrix into LDS slot (atomic loads)
    auto stageA = [&](int slot, const _Float16* src) {
        __syncthreads();
        #pragma unroll
        for (int rep = 0; rep < 4; ++rep) {
            int idx = tid + rep * 256;
            int row = idx >> 6, seg = idx & 63;
            *(f16x8*)&ldsP[slot][row * LDSROW + seg * 8] =
                ald16(&src[(size_t)(R + row) * 512 + seg * 8]);
        }
        __syncthreads();
    };

    // acc += Panel(LDS,slot)[16x512] @ Right_cm[:, c]   (16 MFMAs, K=512)
    auto gpassA = [&](int slot, const _Float16* rcm, f32x4& acc) {
        const _Float16* zc = rcm + (size_t)c * 512;
        #pragma unroll
        for (int kk = 0; kk < 16; ++kk) {
            f16x8 a = *(f16x8*)&ldsP[slot][nI * LDSROW + kk * 32 + q * 8];
            f16x8 b = ald16(&zc[kk * 32 + q * 8]);
            acc = __builtin_amdgcn_mfma_f32_16x16x32_f16(a, b, acc, 0, 0, 0);
        }
    };

    // ---- setup: rowsums of A for rows R..R+15 (block-local) ----
    {
        int row16 = tid >> 4, seg = tid & 15;
        const float4* ap = (const float4*)&A[(size_t)(R + row16) * 512 + seg * 32];
        float p = 0.f;
        #pragma unroll
        for (int j = 0; j < 8; ++j) { float4 v = ap[j]; p += v.x + v.y + v.z + v.w; }
        #pragma unroll
        for (int off = 1; off <= 8; off <<= 1) p += __shfl_xor(p, off, 64);
        if (seg == 0) drs[row16] = p;
    }
    __syncthreads();
    if (tid < 16)
        dinvs[tid] = 1.f / (drs[tid] + 1.f - A[(size_t)(R + tid) * 512 + (R + tid)]);
    __syncthreads();

    // ---- build B panels in LDS directly from A (block-local, no global B) ----
    for (int idx = tid; idx < 8192; idx += 256) {
        int row = idx >> 9, cc = idx & 511;
        float val = ((cc == R + row) ? (drs[row] + 1.f) : 0.f) - A[(size_t)(R + row) * 512 + cc];
        _Float16 hi = (_Float16)val;
        ldsP[0][row * LDSROW + cc] = hi;
        ldsP[1][row * LDSROW + cc] = (_Float16)(val - (float)hi);
    }

    // ---- init X: fp32 master in registers; f16 copies to global ----
    f32x4 Xr;
    {
        f16x4 h4, l4;
        #pragma unroll
        for (int r4 = 0; r4 < 4; ++r4) {
            int row = R + q * 4 + r4;
            float xv = (row == c) ? dinvs[row - R] : 0.f;
            Xr[r4] = xv;
            float s = xv * 256.f;
            h4[r4] = (_Float16)s;
            l4[r4] = (_Float16)(s - (float)h4[r4]);
        }
        ast8(&Xhcm[(size_t)c * 512 + R + q * 4], pack4(h4));
        ast8(&Xlcm[(size_t)c * 512 + R + q * 4], pack4(l4));
        // row-major scatter: pair adjacent lanes into u32 stores
        #pragma unroll
        for (int r4 = 0; r4 < 4; ++r4) {
            int row = R + q * 4 + r4;
            union { _Float16 h; unsigned short s; } cv; cv.h = h4[r4];
            unsigned x = cv.s;
            unsigned px = (unsigned)__shfl_xor((int)x, 1, 64);
            if ((nI & 1) == 0)
                ast4(&Xrm0[(size_t)row * 512 + c], x | (px << 16));
        }
    }
    fbar();

    // ---- Newton iterations ----
    for (int nit = 0; nit < NITER; ++nit) {
        const _Float16* Xrm_cur = (nit & 1) ? Xrm1 : Xrm0;
        _Float16*       Xrm_nxt = (nit & 1) ? Xrm0 : Xrm1;

        // E = I - B@X ; acc = 256*(B@X)
        f32x4 acc = {0.f, 0.f, 0.f, 0.f};
        gpassA(0, Xhcm, acc);
        if (nit >= NPRE) {                 // split-precision only near convergence
            gpassA(0, Xlcm, acc);
            gpassA(1, Xhcm, acc);
        }
        f16x4 ev;
        #pragma unroll
        for (int r4 = 0; r4 < 4; ++r4) {
            int row = R + q * 4 + r4;
            float e = ((row == c) ? 1.f : 0.f) - acc[r4] * (1.f / 256.f);
            ev[r4] = (_Float16)(e * 32.f);
        }
        ast8(&Ecm[(size_t)c * 512 + R + q * 4], pack4(ev));
        fbar();

        // dX = X@E ; acc2 = (256X)@(32E) = 8192*(X@E)
        stageA(2, Xrm_cur);
        f32x4 acc2 = {0.f, 0.f, 0.f, 0.f};
        gpassA(2, Ecm, acc2);
        f16x4 h4, l4;
        #pragma unroll
        for (int r4 = 0; r4 < 4; ++r4) {
            float xv = Xr[r4] + acc2[r4] * (1.f / 8192.f);
            Xr[r4] = xv;
            float s = xv * 256.f;
            h4[r4] = (_Float16)s;
            l4[r4] = (_Float16)(s - (float)h4[r4]);
        }
        ast8(&Xhcm[(size_t)c * 512 + R + q * 4], pack4(h4));
        ast8(&Xlcm[(size_t)c * 512 + R + q * 4], pack4(l4));
        #pragma unroll
        for (int r4 = 0; r4 < 4; ++r4) {
            int row = R + q * 4 + r4;
            union { _Float16 h; unsigned short s; } cv; cv.h = h4[r4];
            unsigned x = cv.s;
            unsigned px = (unsigned)__shfl_xor((int)x, 1, 64);
            if ((nI & 1) == 0)
                ast4(&Xrm_nxt[(size_t)row * 512 + c], x | (px << 16));
        }
        fbar();
    }
    // NITER even -> final X in Xrm0 (== Mrm for the scan kernel)
}

// ---------------------------------------------------------------------------
// Kernel B: barrier-free scan. 32 blocks x 512 threads.
// Block = (batch jt = bx>>2, col-group cg = bx&3): 16 columns, all 512 rows.
// Wave w owns rows [w*64, w*64+64) = 4 row-tiles; tiles 0,1 pinned in VGPRs,
// tiles 2,3 streamed from L2. Z (x_t - y_{t-1}) lives in LDS only.
// ---------------------------------------------------------------------------
__launch_bounds__(512)
__global__ void scan_kernel(const float* __restrict__ xs, const _Float16* __restrict__ Mrm,
                            float* __restrict__ out)
{
    const int tid  = threadIdx.x;
    const int lane = tid & 63;
    const int wv   = tid >> 6;          // wave 0..7
    const int q    = lane >> 4;
    const int nI   = lane & 15;
    const int bx   = blockIdx.x;
    const int jt   = bx >> 2;           // batch
    const int cg   = bx & 3;            // column group
    const int rowbase = wv * 64;
    const int f    = cg * 16 + nI;      // feature column

    __shared__ _Float16 Z[16 * LDSROW]; // col-major: Z[col*520 + k], 16 local cols

    // preload M fragments for tiles 0,1 into VGPRs (held for all 128 steps)
    f16x8 a0[16], a1[16];
    #pragma unroll
    for (int kk = 0; kk < 16; ++kk)
        a0[kk] = *(const f16x8*)&Mrm[(size_t)(rowbase + nI) * 512 + kk * 32 + q * 8];
    #pragma unroll
    for (int kk = 0; kk < 16; ++kk)
        a1[kk] = *(const f16x8*)&Mrm[(size_t)(rowbase + 16 + nI) * 512 + kk * 32 + q * 8];
    const _Float16* m2 = &Mrm[(size_t)(rowbase + 32 + nI) * 512];
    const _Float16* m3 = &Mrm[(size_t)(rowbase + 48 + nI) * 512];

    f32x4 Y[4] = {{0.f,0.f,0.f,0.f},{0.f,0.f,0.f,0.f},{0.f,0.f,0.f,0.f},{0.f,0.f,0.f,0.f}};

    for (int t = 0; t < 128; ++t) {
        const size_t base = ((size_t)(jt * 128 + t) * 512) * 64 + f;

        // z_t = x_t - y_{t-1} for this lane's 16 elements -> LDS (col-major)
        #pragma unroll
        for (int T = 0; T < 4; ++T) {
            f16x4 zv;
            #pragma unroll
            for (int r4 = 0; r4 < 4; ++r4) {
                int row = rowbase + T * 16 + q * 4 + r4;
                float xv = xs[base + (size_t)row * 64];
                zv[r4] = (_Float16)(xv - Y[T][r4]);
            }
            *(f16x4*)&Z[nI * LDSROW + rowbase + T * 16 + q * 4] = zv;
        }
        __syncthreads();

        // acc_T = (256M)[tile rows] @ z    (K=512)
        f32x4 acc0 = {0.f,0.f,0.f,0.f}, acc1 = {0.f,0.f,0.f,0.f};
        f32x4 acc2 = {0.f,0.f,0.f,0.f}, acc3 = {0.f,0.f,0.f,0.f};
        #pragma unroll
        for (int kk = 0; kk < 16; ++kk) {
            f16x8 b  = *(const f16x8*)&Z[nI * LDSROW + kk * 32 + q * 8];
            f16x8 a2 = *(const f16x8*)&m2[kk * 32 + q * 8];
            f16x8 a3 = *(const f16x8*)&m3[kk * 32 + q * 8];
            acc0 = __builtin_amdgcn_mfma_f32_16x16x32_f16(a0[kk], b, acc0, 0, 0, 0);
            acc1 = __builtin_amdgcn_mfma_f32_16x16x32_f16(a1[kk], b, acc1, 0, 0, 0);
            acc2 = __builtin_amdgcn_mfma_f32_16x16x32_f16(a2,     b, acc2, 0, 0, 0);
            acc3 = __builtin_amdgcn_mfma_f32_16x16x32_f16(a3,     b, acc3, 0, 0, 0);
        }

        // y_t = y_{t-1} + acc/256 ; store out
        #pragma unroll
        for (int r4 = 0; r4 < 4; ++r4) {
            Y[0][r4] += acc0[r4] * (1.f / 256.f);
            Y[1][r4] += acc1[r4] * (1.f / 256.f);
            Y[2][r4] += acc2[r4] * (1.f / 256.f);
            Y[3][r4] += acc3[r4] * (1.f / 256.f);
        }
        #pragma unroll
        for (int T = 0; T < 4; ++T)
            #pragma unroll
            for (int r4 = 0; r4 < 4; ++r4) {
                int row = rowbase + T * 16 + q * 4 + r4;
                out[base + (size_t)row * 64] = Y[T][r4];
            }
        __syncthreads();   // WAR: all ds_reads of Z_t done before Z_{t+1} writes
    }
}

extern "C" void kernel_launch(void* const* d_in, const int* in_sizes, int n_in,
                              void* d_out, int out_size, void* d_ws, size_t ws_size,
                              hipStream_t stream)
{
    const float* xs = (const float*)d_in[0];   // [8,128,512,64] fp32
    const float* A  = (const float*)d_in[1];   // [1,512,512] fp32
    float* out = (float*)d_out;                // [8,128,512,64] fp32
    unsigned char* ws = (unsigned char*)d_ws;  // ~2.6 MB used

    // zero the flag region (ws is poisoned 0xAA before every timed launch)
    hipMemsetAsync(d_ws, 0, 16384, stream);

    void* args[] = { (void*)&A, (void*)&ws };
    hipLaunchCooperativeKernel((void*)newton_kernel, dim3(256), dim3(256), args, 0, stream);

    const _Float16* Mrm = (const _Float16*)(ws + 16384);  // Xrm0 == f16(256*M)
    scan_kernel<<<dim3(32), dim3(512), 0, stream>>>(xs, Mrm, out);
}

// Round 3
// 1148.736 us; speedup vs baseline: 3.8754x; 1.2692x over previous
//
#include <hip/hip_runtime.h>

// TGSR: y_t = y_{t-1} + M (x_t - y_{t-1}),  M = inv(L+I) = inv(B).
// Kernel A (cooperative): Newton inverse with Sherman-Morrison rank-1 start
//   (B*1 = 1 exactly -> deflate the slow mode; 3 plain + 2 split iters).
// Kernel B (plain): 128-step scan, 32 blocks x 512 threads, no spills
//   (launch_bounds(512,2) -> 256 VGPR), Z double-buffered in LDS, 1 sync/step.

#define NITER 5
#define NPRE  3     // split-precision (3-product) E for nit >= NPRE

typedef _Float16 f16x8 __attribute__((ext_vector_type(8)));
typedef _Float16 f16x4 __attribute__((ext_vector_type(4)));
typedef float    f32x4 __attribute__((ext_vector_type(4)));
typedef unsigned long long u64;

#define LDSROW 520   // Newton LDS row pitch (f16)
#define ZROW   536   // scan Z row pitch (f16): 16B-aligned rows, good bank spread

__device__ __forceinline__ u64 ald8(const void* p) {
    return __hip_atomic_load((const u64*)p, __ATOMIC_RELAXED, __HIP_MEMORY_SCOPE_AGENT);
}
__device__ __forceinline__ void ast8(void* p, u64 v) {
    __hip_atomic_store((u64*)p, v, __ATOMIC_RELAXED, __HIP_MEMORY_SCOPE_AGENT);
}
__device__ __forceinline__ void ast4(void* p, unsigned v) {
    __hip_atomic_store((unsigned*)p, v, __ATOMIC_RELAXED, __HIP_MEMORY_SCOPE_AGENT);
}
__device__ __forceinline__ void astf(void* p, float v) {
    union { float f; unsigned u; } t; t.f = v;
    ast4(p, t.u);
}
__device__ __forceinline__ float alf(const void* p) {
    union { float f; unsigned u; } t;
    t.u = __hip_atomic_load((const unsigned*)p, __ATOMIC_RELAXED, __HIP_MEMORY_SCOPE_AGENT);
    return t.f;
}
__device__ __forceinline__ f16x8 ald16(const void* p) {
    union { u64 u[2]; f16x8 v; } t;
    t.u[0] = ald8(p);
    t.u[1] = ald8((const u64*)p + 1);
    return t.v;
}
__device__ __forceinline__ u64 pack4(f16x4 v) {
    union { f16x4 v; u64 u; } t; t.v = v; return t.u;
}

// ---------------------------------------------------------------------------
// Kernel A: Newton X <- X + X(I - B X), B = (D+1)I - A.
// 256 blocks x 256 threads (cooperative); flag barrier; agent-scope exchange.
// ---------------------------------------------------------------------------
__launch_bounds__(256, 1)
__global__ void newton_kernel(const float* __restrict__ A, unsigned char* __restrict__ wsb)
{
    unsigned* flags = (unsigned*)wsb;                 // 256 flags, 64 B apart
    float*    wglob = (float*)(wsb + 16384);          // w_i = 1/(1+d_i), 512 floats
    _Float16* Xrm0 = (_Float16*)(wsb + 32768);        // f16(256*X), row-major (ping)
    _Float16* Xrm1 = Xrm0 + 262144;                   // pong (NITER odd -> final here)
    _Float16* Xhcm = Xrm1 + 262144;                   // f16 hi(256*X), col-major [c][k]
    _Float16* Xlcm = Xhcm + 262144;                   // f16 lo(256*X), col-major
    _Float16* Ecm  = Xlcm + 262144;                   // f16(32*E), col-major

    const int tid  = threadIdx.x;
    const int lane = tid & 63;
    const int w    = tid >> 6;
    const int q    = lane >> 4;
    const int nI   = lane & 15;
    const int bx   = blockIdx.x;
    const int jt   = bx & 7;
    const int R    = (bx >> 3) * 16;
    const int c    = jt * 64 + w * 16 + nI;

    __shared__ _Float16 ldsP[3][16 * LDSROW];   // slot0 Bhi, slot1 Blo, slot2 staging
    __shared__ float drs[16], ws16[16], red[4];

    unsigned bt = 0;
    auto fbar = [&]() {
        ++bt;
        __syncthreads();
        if (tid == 0)
            __hip_atomic_store(&flags[bx * 16], bt, __ATOMIC_RELAXED, __HIP_MEMORY_SCOPE_AGENT);
        while (__hip_atomic_load(&flags[tid * 16], __ATOMIC_RELAXED, __HIP_MEMORY_SCOPE_AGENT) < bt)
            __builtin_amdgcn_s_sleep(2);
        __syncthreads();
    };

    auto stageA = [&](int slot, const _Float16* src) {
        __syncthreads();
        #pragma unroll
        for (int rep = 0; rep < 4; ++rep) {
            int idx = tid + rep * 256;
            int row = idx >> 6, seg = idx & 63;
            *(f16x8*)&ldsP[slot][row * LDSROW + seg * 8] =
                ald16(&src[(size_t)(R + row) * 512 + seg * 8]);
        }
        __syncthreads();
    };

    auto gpassA = [&](int slot, const _Float16* rcm, f32x4& acc) {
        const _Float16* zc = rcm + (size_t)c * 512;
        #pragma unroll
        for (int kk = 0; kk < 16; ++kk) {
            f16x8 a = *(f16x8*)&ldsP[slot][nI * LDSROW + kk * 32 + q * 8];
            f16x8 b = ald16(&zc[kk * 32 + q * 8]);
            acc = __builtin_amdgcn_mfma_f32_16x16x32_f16(a, b, acc, 0, 0, 0);
        }
    };

    // ---- rowsums d_i for local rows; w_i = 1/(1+d_i); publish w ----
    {
        int row16 = tid >> 4, seg = tid & 15;
        const float4* ap = (const float4*)&A[(size_t)(R + row16) * 512 + seg * 32];
        float p = 0.f;
        #pragma unroll
        for (int j = 0; j < 8; ++j) { float4 v = ap[j]; p += v.x + v.y + v.z + v.w; }
        #pragma unroll
        for (int off = 1; off <= 8; off <<= 1) p += __shfl_xor(p, off, 64);
        if (seg == 0) drs[row16] = p;
    }
    __syncthreads();
    if (tid < 16) {
        float wv = 1.f / (1.f + drs[tid]);
        ws16[tid] = wv;
        astf(&wglob[R + tid], wv);
    }
    __syncthreads();

    // ---- build exact B panels in LDS (block-local) ----
    for (int idx = tid; idx < 8192; idx += 256) {
        int row = idx >> 9, cc = idx & 511;
        float val = ((cc == R + row) ? (drs[row] + 1.f) : 0.f) - A[(size_t)(R + row) * 512 + cc];
        _Float16 hi = (_Float16)val;
        ldsP[0][row * LDSROW + cc] = hi;
        ldsP[1][row * LDSROW + cc] = (_Float16)(val - (float)hi);
    }
    fbar();   // w visible everywhere

    // ---- s = sum_i w_i ----
    float s;
    {
        float p = alf(&wglob[tid]) + alf(&wglob[tid + 256]);
        #pragma unroll
        for (int off = 32; off >= 1; off >>= 1) p += __shfl_xor(p, off, 64);
        if (lane == 0) red[w] = p;
        __syncthreads();
        s = red[0] + red[1] + red[2] + red[3];
        __syncthreads();
    }

    // ---- X0 = W + (1-w) w^T / s   (Sherman-Morrison; deflates B's 1-mode) ----
    f32x4 Xr;
    {
        float wc = alf(&wglob[c]);
        f16x4 h4, l4;
        #pragma unroll
        for (int r4 = 0; r4 < 4; ++r4) {
            int row = R + q * 4 + r4;
            float wr = ws16[row - R];
            float xv = ((row == c) ? wr : 0.f) + (1.f - wr) * wc / s;
            Xr[r4] = xv;
            float sc = xv * 256.f;
            h4[r4] = (_Float16)sc;
            l4[r4] = (_Float16)(sc - (float)h4[r4]);
        }
        ast8(&Xhcm[(size_t)c * 512 + R + q * 4], pack4(h4));
        ast8(&Xlcm[(size_t)c * 512 + R + q * 4], pack4(l4));
        #pragma unroll
        for (int r4 = 0; r4 < 4; ++r4) {
            int row = R + q * 4 + r4;
            union { _Float16 h; unsigned short s; } cv; cv.h = h4[r4];
            unsigned x = cv.s;
            unsigned px = (unsigned)__shfl_xor((int)x, 1, 64);
            if ((nI & 1) == 0)
                ast4(&Xrm0[(size_t)row * 512 + c], x | (px << 16));
        }
    }
    fbar();

    // ---- Newton iterations ----
    for (int nit = 0; nit < NITER; ++nit) {
        const _Float16* Xrm_cur = (nit & 1) ? Xrm1 : Xrm0;
        _Float16*       Xrm_nxt = (nit & 1) ? Xrm0 : Xrm1;

        // E = I - B@X ; acc = 256*(B@X)
        f32x4 acc = {0.f, 0.f, 0.f, 0.f};
        gpassA(0, Xhcm, acc);
        if (nit >= NPRE) {
            gpassA(0, Xlcm, acc);
            gpassA(1, Xhcm, acc);
        }
        f16x4 ev;
        #pragma unroll
        for (int r4 = 0; r4 < 4; ++r4) {
            int row = R + q * 4 + r4;
            float e = ((row == c) ? 1.f : 0.f) - acc[r4] * (1.f / 256.f);
            ev[r4] = (_Float16)(e * 32.f);
        }
        ast8(&Ecm[(size_t)c * 512 + R + q * 4], pack4(ev));
        fbar();

        // X += X@E ; acc2 = (256X)@(32E) = 8192*(X@E)
        stageA(2, Xrm_cur);
        f32x4 acc2 = {0.f, 0.f, 0.f, 0.f};
        gpassA(2, Ecm, acc2);
        f16x4 h4, l4;
        #pragma unroll
        for (int r4 = 0; r4 < 4; ++r4) {
            float xv = Xr[r4] + acc2[r4] * (1.f / 8192.f);
            Xr[r4] = xv;
            float sc = xv * 256.f;
            h4[r4] = (_Float16)sc;
            l4[r4] = (_Float16)(sc - (float)h4[r4]);
        }
        ast8(&Xhcm[(size_t)c * 512 + R + q * 4], pack4(h4));
        ast8(&Xlcm[(size_t)c * 512 + R + q * 4], pack4(l4));
        #pragma unroll
        for (int r4 = 0; r4 < 4; ++r4) {
            int row = R + q * 4 + r4;
            union { _Float16 h; unsigned short s; } cv; cv.h = h4[r4];
            unsigned x = cv.s;
            unsigned px = (unsigned)__shfl_xor((int)x, 1, 64);
            if ((nI & 1) == 0)
                ast4(&Xrm_nxt[(size_t)row * 512 + c], x | (px << 16));
        }
        fbar();
    }
}

// ---------------------------------------------------------------------------
// Kernel B: barrier-free scan. 32 blocks x 512 threads, 256 VGPR budget.
// Tiles 0,1 of M pinned in VGPRs; tiles 2,3 streamed from L2; Z double-
// buffered in LDS (1 syncthreads/step); xs prefetched 2 steps ahead.
// ---------------------------------------------------------------------------
__launch_bounds__(512, 2)
__global__ void scan_kernel(const float* __restrict__ xs, const _Float16* __restrict__ Mrm,
                            float* __restrict__ out)
{
    const int tid  = threadIdx.x;
    const int lane = tid & 63;
    const int wv   = tid >> 6;          // wave 0..7
    const int q    = lane >> 4;
    const int nI   = lane & 15;
    const int bx   = blockIdx.x;
    const int jt   = bx >> 2;           // batch
    const int cg   = bx & 3;            // column group
    const int rowbase = wv * 64;
    const int f    = cg * 16 + nI;      // feature column

    __shared__ _Float16 Z[2][16 * ZROW];

    // pin M fragments for row-tiles 0,1 (held in VGPRs for all 128 steps)
    f16x8 a0[16], a1[16];
    #pragma unroll
    for (int kk = 0; kk < 16; ++kk)
        a0[kk] = *(const f16x8*)&Mrm[(size_t)(rowbase + nI) * 512 + kk * 32 + q * 8];
    #pragma unroll
    for (int kk = 0; kk < 16; ++kk)
        a1[kk] = *(const f16x8*)&Mrm[(size_t)(rowbase + 16 + nI) * 512 + kk * 32 + q * 8];
    const _Float16* m2 = &Mrm[(size_t)(rowbase + 32 + nI) * 512];
    const _Float16* m3 = &Mrm[(size_t)(rowbase + 48 + nI) * 512];

    f32x4 Y[4] = {{0.f,0.f,0.f,0.f},{0.f,0.f,0.f,0.f},{0.f,0.f,0.f,0.f},{0.f,0.f,0.f,0.f}};
    float xn[4][4];

    // z_0 = x_0 (Y=0) -> Z[0]; prefetch x_1
    {
        const size_t b0 = ((size_t)(jt * 128 + 0) * 512) * 64 + f;
        #pragma unroll
        for (int T = 0; T < 4; ++T) {
            f16x4 zv;
            #pragma unroll
            for (int r4 = 0; r4 < 4; ++r4) {
                xn[T][r4] = xs[b0 + (size_t)(rowbase + T * 16 + q * 4 + r4) * 64];
                zv[r4] = (_Float16)xn[T][r4];
            }
            *(f16x4*)&Z[0][nI * ZROW + rowbase + T * 16 + q * 4] = zv;
        }
        const size_t b1 = ((size_t)(jt * 128 + 1) * 512) * 64 + f;
        #pragma unroll
        for (int T = 0; T < 4; ++T)
            #pragma unroll
            for (int r4 = 0; r4 < 4; ++r4)
                xn[T][r4] = xs[b1 + (size_t)(rowbase + T * 16 + q * 4 + r4) * 64];
    }
    __syncthreads();

    for (int t = 0; t < 128; ++t) {
        const _Float16* zb = &Z[t & 1][nI * ZROW];
        f32x4 acc0 = {0.f,0.f,0.f,0.f}, acc1 = {0.f,0.f,0.f,0.f};
        f32x4 acc2 = {0.f,0.f,0.f,0.f}, acc3 = {0.f,0.f,0.f,0.f};
        #pragma unroll
        for (int kk = 0; kk < 16; ++kk) {
            f16x8 b  = *(const f16x8*)&zb[kk * 32 + q * 8];
            f16x8 a2 = *(const f16x8*)&m2[kk * 32 + q * 8];
            f16x8 a3 = *(const f16x8*)&m3[kk * 32 + q * 8];
            acc0 = __builtin_amdgcn_mfma_f32_16x16x32_f16(a0[kk], b, acc0, 0, 0, 0);
            acc1 = __builtin_amdgcn_mfma_f32_16x16x32_f16(a1[kk], b, acc1, 0, 0, 0);
            acc2 = __builtin_amdgcn_mfma_f32_16x16x32_f16(a2,     b, acc2, 0, 0, 0);
            acc3 = __builtin_amdgcn_mfma_f32_16x16x32_f16(a3,     b, acc3, 0, 0, 0);
        }

        const size_t base = ((size_t)(jt * 128 + t) * 512) * 64 + f;
        #pragma unroll
        for (int r4 = 0; r4 < 4; ++r4) {
            Y[0][r4] += acc0[r4] * (1.f / 256.f);
            Y[1][r4] += acc1[r4] * (1.f / 256.f);
            Y[2][r4] += acc2[r4] * (1.f / 256.f);
            Y[3][r4] += acc3[r4] * (1.f / 256.f);
        }
        #pragma unroll
        for (int T = 0; T < 4; ++T)
            #pragma unroll
            for (int r4 = 0; r4 < 4; ++r4)
                out[base + (size_t)(rowbase + T * 16 + q * 4 + r4) * 64] = Y[T][r4];

        if (t < 127) {
            _Float16* zn = &Z[(t + 1) & 1][nI * ZROW];
            #pragma unroll
            for (int T = 0; T < 4; ++T) {
                f16x4 zv;
                #pragma unroll
                for (int r4 = 0; r4 < 4; ++r4)
                    zv[r4] = (_Float16)(xn[T][r4] - Y[T][r4]);
                *(f16x4*)&zn[rowbase + T * 16 + q * 4] = zv;
            }
            if (t < 126) {   // prefetch x_{t+2}
                const size_t bn = ((size_t)(jt * 128 + t + 2) * 512) * 64 + f;
                #pragma unroll
                for (int T = 0; T < 4; ++T)
                    #pragma unroll
                    for (int r4 = 0; r4 < 4; ++r4)
                        xn[T][r4] = xs[bn + (size_t)(rowbase + T * 16 + q * 4 + r4) * 64];
            }
            __syncthreads();
        }
    }
}

extern "C" void kernel_launch(void* const* d_in, const int* in_sizes, int n_in,
                              void* d_out, int out_size, void* d_ws, size_t ws_size,
                              hipStream_t stream)
{
    const float* xs = (const float*)d_in[0];   // [8,128,512,64] fp32
    const float* A  = (const float*)d_in[1];   // [1,512,512] fp32
    float* out = (float*)d_out;                // [8,128,512,64] fp32
    unsigned char* ws = (unsigned char*)d_ws;  // ~2.7 MB used

    hipMemsetAsync(d_ws, 0, 16384, stream);    // flag region only

    void* args[] = { (void*)&A, (void*)&ws };
    hipLaunchCooperativeKernel((void*)newton_kernel, dim3(256), dim3(256), args, 0, stream);

    // NITER odd -> final f16(256*M) row-major is in Xrm1
    const _Float16* Mrm = (const _Float16*)(ws + 32768 + ((NITER & 1) ? 524288 : 0));
    scan_kernel<<<dim3(32), dim3(512), 0, stream>>>(xs, Mrm, out);
}

// Round 4
// 867.267 us; speedup vs baseline: 5.1331x; 1.3245x over previous
//
#include <hip/hip_runtime.h>

// TGSR: y_t = y_{t-1} + M (x_t - y_{t-1}),  M = inv(L+I) = inv(B).
// R4: all plain kernel launches (kernel boundary = device-wide sync+coherence).
//  - Newton inverse: 2 launches/iter, Sherman-Morrison rank-1 start, 5 iters.
//  - G-powers: G=I-M, 4 hi/lo-split squarings -> G^16 (for chunk carries).
//  - Chunked scan, C=8 chunks of 16 steps: phase1 (local scans -> end states),
//    7 carry GEMMs (Y_c = E_c + G16 Y_{c-1}), phase2 (re-scan with carry-in).

#define NITER 5
#define NPRE  3

typedef _Float16 f16x8 __attribute__((ext_vector_type(8)));
typedef _Float16 f16x4 __attribute__((ext_vector_type(4)));
typedef float    f32x4 __attribute__((ext_vector_type(4)));

#define LDSROW 520
#define ZROW   520

// ---- workspace offsets (bytes) ----
#define OFF_W      0u          // 512 f32
#define OFF_BHI    8192u       // f16 hi(B) row-major        512 KB
#define OFF_BLO    532480u     // f16 lo(B) row-major        512 KB
#define OFF_XF     1056768u    // fp32 X, col-major          1 MB
#define OFF_XRM0   2105344u    // f16(256X) row-major ping   512 KB
#define OFF_XRM1   2629632u    // pong (NITER odd -> final M here)
#define OFF_XHCM   3153920u    // f16 hi(256X) col-major
#define OFF_XLCM   3678208u    // f16 lo(256X) col-major
#define OFF_ECM    4202496u    // f16(32E) col-major
#define OFF_G0     4726784u    // G buf0: [rm_h, rm_l, cm_h, cm_l] x 512 KB = 2 MB
#define OFF_G1     6823936u    // G buf1: same layout
#define OFF_STATE  8921088u    // f16 carry states [c][jt][f][row] = 4 MB
// total ~12.6 MB

#define GSUB 262144  // elements per G sub-array

__device__ __forceinline__ f32x4 MF(f16x8 a, f16x8 b, f32x4 c) {
    return __builtin_amdgcn_mfma_f32_16x16x32_f16(a, b, c, 0, 0, 0);
}
__device__ __forceinline__ unsigned long long pack4(f16x4 v) {
    union { f16x4 v; unsigned long long u; } t; t.v = v; return t.u;
}

// ---------------------------------------------------------------------------
// K1a: rowsums -> w; build B = (D+1)I - A as f16 hi/lo row-major.
// 32 blocks x 256 threads, block owns rows R..R+15.
// ---------------------------------------------------------------------------
__launch_bounds__(256)
__global__ void k_prep_rows(const float* __restrict__ A, unsigned char* __restrict__ wsb)
{
    float* w = (float*)(wsb + OFF_W);
    _Float16* Bhi = (_Float16*)(wsb + OFF_BHI);
    _Float16* Blo = (_Float16*)(wsb + OFF_BLO);
    const int tid = threadIdx.x;
    const int R = blockIdx.x * 16;
    __shared__ float drs[16];
    {
        int row16 = tid >> 4, seg = tid & 15;
        const float4* ap = (const float4*)&A[(size_t)(R + row16) * 512 + seg * 32];
        float p = 0.f;
        #pragma unroll
        for (int j = 0; j < 8; ++j) { float4 v = ap[j]; p += v.x + v.y + v.z + v.w; }
        #pragma unroll
        for (int off = 1; off <= 8; off <<= 1) p += __shfl_xor(p, off, 64);
        if (seg == 0) drs[row16] = p;
    }
    __syncthreads();
    if (tid < 16) w[R + tid] = 1.f / (1.f + drs[tid]);
    for (int idx = tid; idx < 8192; idx += 256) {
        int row = idx >> 9, cc = idx & 511;
        float val = ((cc == R + row) ? (drs[row] + 1.f) : 0.f) - A[(size_t)(R + row) * 512 + cc];
        _Float16 hi = (_Float16)val;
        Bhi[(size_t)(R + row) * 512 + cc] = hi;
        Blo[(size_t)(R + row) * 512 + cc] = (_Float16)(val - (float)hi);
    }
}

// ---------------------------------------------------------------------------
// K1b: X0 = W + (1-w) w^T / s  (Sherman-Morrison start; deflates B's 1-mode).
// 32 blocks x 256 threads, block owns cols C..C+15.
// ---------------------------------------------------------------------------
__launch_bounds__(256)
__global__ void k_init_x(unsigned char* __restrict__ wsb)
{
    const float* w = (const float*)(wsb + OFF_W);
    float*    Xf  = (float*)(wsb + OFF_XF);
    _Float16* Xh  = (_Float16*)(wsb + OFF_XHCM);
    _Float16* Xl  = (_Float16*)(wsb + OFF_XLCM);
    _Float16* Xrm = (_Float16*)(wsb + OFF_XRM0);
    const int tid = threadIdx.x;
    const int C = blockIdx.x * 16;
    __shared__ float wl[512];
    __shared__ float red[4];
    wl[tid] = w[tid]; wl[tid + 256] = w[tid + 256];
    __syncthreads();
    float p = wl[tid] + wl[tid + 256];
    #pragma unroll
    for (int off = 32; off >= 1; off >>= 1) p += __shfl_xor(p, off, 64);
    if ((tid & 63) == 0) red[tid >> 6] = p;
    __syncthreads();
    const float s = red[0] + red[1] + red[2] + red[3];
    for (int idx = tid; idx < 8192; idx += 256) {
        int col = C + (idx >> 9), row = idx & 511;
        float wr = wl[row];
        float xv = ((row == col) ? wr : 0.f) + (1.f - wr) * wl[col] / s;
        Xf[(size_t)col * 512 + row] = xv;
        float sc = xv * 256.f;
        _Float16 h = (_Float16)sc;
        Xh[(size_t)col * 512 + row] = h;
        Xl[(size_t)col * 512 + row] = (_Float16)(sc - (float)h);
        Xrm[(size_t)row * 512 + col] = h;
    }
}

// ---------------------------------------------------------------------------
// K2: E = I - B@X   (acc = 256*(B@X); split 3-product for nit >= NPRE)
// 256 blocks x 256 threads: block (P=bx>>3 -> rows P*16.., jt=bx&7 -> cols jt*64..)
// ---------------------------------------------------------------------------
__launch_bounds__(256)
__global__ void k_newton_e(unsigned char* __restrict__ wsb, int nit)
{
    const _Float16* Bhi = (const _Float16*)(wsb + OFF_BHI);
    const _Float16* Blo = (const _Float16*)(wsb + OFF_BLO);
    const _Float16* Xh  = (const _Float16*)(wsb + OFF_XHCM);
    const _Float16* Xl  = (const _Float16*)(wsb + OFF_XLCM);
    _Float16* Ecm = (_Float16*)(wsb + OFF_ECM);

    const int tid = threadIdx.x;
    const int lane = tid & 63, w = tid >> 6, q = lane >> 4, nI = lane & 15;
    const int bx = blockIdx.x;
    const int jt = bx & 7, R = (bx >> 3) * 16;
    const int c = jt * 64 + w * 16 + nI;

    __shared__ _Float16 pan[2][16 * LDSROW];
    #pragma unroll
    for (int rep = 0; rep < 4; ++rep) {
        int idx = tid + rep * 256; int row = idx >> 6, seg = idx & 63;
        *(f16x8*)&pan[0][row * LDSROW + seg * 8] = *(const f16x8*)&Bhi[(size_t)(R + row) * 512 + seg * 8];
        *(f16x8*)&pan[1][row * LDSROW + seg * 8] = *(const f16x8*)&Blo[(size_t)(R + row) * 512 + seg * 8];
    }
    __syncthreads();

    const _Float16* xh = Xh + (size_t)c * 512;
    const _Float16* xl = Xl + (size_t)c * 512;
    f32x4 acc = {0.f, 0.f, 0.f, 0.f};
    #pragma unroll
    for (int kk = 0; kk < 16; ++kk)
        acc = MF(*(f16x8*)&pan[0][nI * LDSROW + kk * 32 + q * 8], *(const f16x8*)&xh[kk * 32 + q * 8], acc);
    if (nit >= NPRE) {
        #pragma unroll
        for (int kk = 0; kk < 16; ++kk)
            acc = MF(*(f16x8*)&pan[0][nI * LDSROW + kk * 32 + q * 8], *(const f16x8*)&xl[kk * 32 + q * 8], acc);
        #pragma unroll
        for (int kk = 0; kk < 16; ++kk)
            acc = MF(*(f16x8*)&pan[1][nI * LDSROW + kk * 32 + q * 8], *(const f16x8*)&xh[kk * 32 + q * 8], acc);
    }
    f16x4 ev;
    #pragma unroll
    for (int r4 = 0; r4 < 4; ++r4) {
        int row = R + q * 4 + r4;
        float e = ((row == c) ? 1.f : 0.f) - acc[r4] * (1.f / 256.f);
        ev[r4] = (_Float16)(e * 32.f);
    }
    *(f16x4*)&Ecm[(size_t)c * 512 + R + q * 4] = ev;
}

// ---------------------------------------------------------------------------
// K3: X += X@E   (acc = (256X)@(32E) = 8192*(X@E)); fp32 master in Xf (cm).
// ---------------------------------------------------------------------------
__launch_bounds__(256)
__global__ void k_newton_u(unsigned char* __restrict__ wsb, int nit)
{
    const _Float16* Xrm_cur = (const _Float16*)(wsb + ((nit & 1) ? OFF_XRM1 : OFF_XRM0));
    _Float16*       Xrm_nxt = (_Float16*)(wsb + ((nit & 1) ? OFF_XRM0 : OFF_XRM1));
    const _Float16* Ecm = (const _Float16*)(wsb + OFF_ECM);
    float*    Xf = (float*)(wsb + OFF_XF);
    _Float16* Xh = (_Float16*)(wsb + OFF_XHCM);
    _Float16* Xl = (_Float16*)(wsb + OFF_XLCM);

    const int tid = threadIdx.x;
    const int lane = tid & 63, w = tid >> 6, q = lane >> 4, nI = lane & 15;
    const int bx = blockIdx.x;
    const int jt = bx & 7, R = (bx >> 3) * 16;
    const int c = jt * 64 + w * 16 + nI;

    __shared__ _Float16 pan[16 * LDSROW];
    #pragma unroll
    for (int rep = 0; rep < 4; ++rep) {
        int idx = tid + rep * 256; int row = idx >> 6, seg = idx & 63;
        *(f16x8*)&pan[row * LDSROW + seg * 8] = *(const f16x8*)&Xrm_cur[(size_t)(R + row) * 512 + seg * 8];
    }
    __syncthreads();

    const _Float16* ec = Ecm + (size_t)c * 512;
    f32x4 acc = {0.f, 0.f, 0.f, 0.f};
    #pragma unroll
    for (int kk = 0; kk < 16; ++kk)
        acc = MF(*(f16x8*)&pan[nI * LDSROW + kk * 32 + q * 8], *(const f16x8*)&ec[kk * 32 + q * 8], acc);

    f32x4 xv4 = *(f32x4*)&Xf[(size_t)c * 512 + R + q * 4];
    f16x4 h4, l4;
    #pragma unroll
    for (int r4 = 0; r4 < 4; ++r4) {
        float xv = xv4[r4] + acc[r4] * (1.f / 8192.f);
        xv4[r4] = xv;
        float sc = xv * 256.f;
        h4[r4] = (_Float16)sc;
        l4[r4] = (_Float16)(sc - (float)h4[r4]);
    }
    *(f32x4*)&Xf[(size_t)c * 512 + R + q * 4] = xv4;
    *(unsigned long long*)&Xh[(size_t)c * 512 + R + q * 4] = pack4(h4);
    *(unsigned long long*)&Xl[(size_t)c * 512 + R + q * 4] = pack4(l4);
    #pragma unroll
    for (int r4 = 0; r4 < 4; ++r4) {
        int row = R + q * 4 + r4;
        union { _Float16 h; unsigned short s; } cv; cv.h = h4[r4];
        unsigned x = cv.s;
        unsigned px = (unsigned)__shfl_xor((int)x, 1, 64);
        if ((nI & 1) == 0)
            *(unsigned*)&Xrm_nxt[(size_t)row * 512 + c] = x | (px << 16);
    }
}

// ---------------------------------------------------------------------------
// K4: G = I - M  ->  G buf0 as 256*G, hi/lo, row-major + col-major.
// 32 blocks x 256 threads, block owns cols C..C+15.
// ---------------------------------------------------------------------------
__launch_bounds__(256)
__global__ void k_gprep(unsigned char* __restrict__ wsb)
{
    const float* Xf = (const float*)(wsb + OFF_XF);
    _Float16* G = (_Float16*)(wsb + OFF_G0);
    _Float16* Grmh = G, *Grml = G + GSUB, *Gcmh = G + 2 * GSUB, *Gcml = G + 3 * GSUB;
    const int tid = threadIdx.x;
    const int C = blockIdx.x * 16;
    for (int idx = tid; idx < 8192; idx += 256) {
        int col = C + (idx >> 9), row = idx & 511;
        float g = ((row == col) ? 1.f : 0.f) - Xf[(size_t)col * 512 + row];
        float sc = g * 256.f;
        _Float16 h = (_Float16)sc;
        _Float16 l = (_Float16)(sc - (float)h);
        Gcmh[(size_t)col * 512 + row] = h;
        Gcml[(size_t)col * 512 + row] = l;
        Grmh[(size_t)row * 512 + col] = h;
        Grml[(size_t)row * 512 + col] = l;
    }
}

// ---------------------------------------------------------------------------
// K5: G2 = G@G (hi/lo split, 3 products). In: 256*G, out: 256*G^2 (same layout).
// ---------------------------------------------------------------------------
__launch_bounds__(256)
__global__ void k_gsq(const _Float16* __restrict__ Gin, _Float16* __restrict__ Gout)
{
    const _Float16* rmh = Gin, *rml = Gin + GSUB, *cmh = Gin + 2 * GSUB, *cml = Gin + 3 * GSUB;
    _Float16* ormh = Gout; _Float16* orml = Gout + GSUB;
    _Float16* ocmh = Gout + 2 * GSUB; _Float16* ocml = Gout + 3 * GSUB;

    const int tid = threadIdx.x;
    const int lane = tid & 63, w = tid >> 6, q = lane >> 4, nI = lane & 15;
    const int bx = blockIdx.x;
    const int jt = bx & 7, R = (bx >> 3) * 16;
    const int c = jt * 64 + w * 16 + nI;

    __shared__ _Float16 pan[2][16 * LDSROW];
    #pragma unroll
    for (int rep = 0; rep < 4; ++rep) {
        int idx = tid + rep * 256; int row = idx >> 6, seg = idx & 63;
        *(f16x8*)&pan[0][row * LDSROW + seg * 8] = *(const f16x8*)&rmh[(size_t)(R + row) * 512 + seg * 8];
        *(f16x8*)&pan[1][row * LDSROW + seg * 8] = *(const f16x8*)&rml[(size_t)(R + row) * 512 + seg * 8];
    }
    __syncthreads();

    const _Float16* bh = cmh + (size_t)c * 512;
    const _Float16* bl = cml + (size_t)c * 512;
    f32x4 acc = {0.f, 0.f, 0.f, 0.f};
    #pragma unroll
    for (int kk = 0; kk < 16; ++kk) {
        f16x8 ah = *(f16x8*)&pan[0][nI * LDSROW + kk * 32 + q * 8];
        f16x8 al = *(f16x8*)&pan[1][nI * LDSROW + kk * 32 + q * 8];
        f16x8 vh = *(const f16x8*)&bh[kk * 32 + q * 8];
        f16x8 vl = *(const f16x8*)&bl[kk * 32 + q * 8];
        acc = MF(ah, vh, acc);
        acc = MF(ah, vl, acc);
        acc = MF(al, vh, acc);
    }
    f16x4 h4, l4;
    #pragma unroll
    for (int r4 = 0; r4 < 4; ++r4) {
        float v = acc[r4] * (1.f / 256.f);   // 256*G^2
        h4[r4] = (_Float16)v;
        l4[r4] = (_Float16)(v - (float)h4[r4]);
    }
    *(unsigned long long*)&ocmh[(size_t)c * 512 + R + q * 4] = pack4(h4);
    *(unsigned long long*)&ocml[(size_t)c * 512 + R + q * 4] = pack4(l4);
    #pragma unroll
    for (int r4 = 0; r4 < 4; ++r4) {
        int row = R + q * 4 + r4;
        union { _Float16 h; unsigned short s; } cv, cl; cv.h = h4[r4]; cl.h = l4[r4];
        unsigned xh = cv.s, xl = cl.s;
        unsigned pxh = (unsigned)__shfl_xor((int)xh, 1, 64);
        unsigned pxl = (unsigned)__shfl_xor((int)xl, 1, 64);
        if ((nI & 1) == 0) {
            *(unsigned*)&ormh[(size_t)row * 512 + c] = xh | (pxh << 16);
            *(unsigned*)&orml[(size_t)row * 512 + c] = xl | (pxl << 16);
        }
    }
}

// ---------------------------------------------------------------------------
// K6: phase-1 local chunk scan (16 steps, zero init), emit end state (f16 cm).
// 256 blocks x 512 threads: bx = chunk*32 + jt*4 + cg.
// ---------------------------------------------------------------------------
__launch_bounds__(512, 2)
__global__ void k_phase1(const float* __restrict__ xs, unsigned char* __restrict__ wsb)
{
    const _Float16* Mrm = (const _Float16*)(wsb + OFF_XRM1);   // NITER odd
    _Float16* state = (_Float16*)(wsb + OFF_STATE);

    const int tid = threadIdx.x;
    const int lane = tid & 63, wv = tid >> 6, q = lane >> 4, nI = lane & 15;
    const int bx = blockIdx.x;
    const int ch = bx >> 5, jt = (bx >> 2) & 7, cg = bx & 3;
    const int rowbase = wv * 64;
    const int f = cg * 16 + nI;

    __shared__ _Float16 Z[2][16 * ZROW];

    f16x8 a0[16], a1[16];
    #pragma unroll
    for (int kk = 0; kk < 16; ++kk)
        a0[kk] = *(const f16x8*)&Mrm[(size_t)(rowbase + nI) * 512 + kk * 32 + q * 8];
    #pragma unroll
    for (int kk = 0; kk < 16; ++kk)
        a1[kk] = *(const f16x8*)&Mrm[(size_t)(rowbase + 16 + nI) * 512 + kk * 32 + q * 8];
    const _Float16* m2 = &Mrm[(size_t)(rowbase + 32 + nI) * 512];
    const _Float16* m3 = &Mrm[(size_t)(rowbase + 48 + nI) * 512];

    f32x4 Y[4] = {{0,0,0,0},{0,0,0,0},{0,0,0,0},{0,0,0,0}};
    float xn[4][4];
    const int tg0 = ch * 16;

    {
        const size_t b0 = ((size_t)(jt * 128 + tg0) * 512) * 64 + f;
        #pragma unroll
        for (int T = 0; T < 4; ++T) {
            f16x4 zv;
            #pragma unroll
            for (int r4 = 0; r4 < 4; ++r4)
                zv[r4] = (_Float16)xs[b0 + (size_t)(rowbase + T * 16 + q * 4 + r4) * 64];
            *(f16x4*)&Z[0][nI * ZROW + rowbase + T * 16 + q * 4] = zv;
        }
        const size_t b1 = ((size_t)(jt * 128 + tg0 + 1) * 512) * 64 + f;
        #pragma unroll
        for (int T = 0; T < 4; ++T)
            #pragma unroll
            for (int r4 = 0; r4 < 4; ++r4)
                xn[T][r4] = xs[b1 + (size_t)(rowbase + T * 16 + q * 4 + r4) * 64];
    }
    __syncthreads();

    for (int t = 0; t < 16; ++t) {
        const _Float16* zb = &Z[t & 1][nI * ZROW];
        f32x4 acc0 = {0,0,0,0}, acc1 = {0,0,0,0}, acc2 = {0,0,0,0}, acc3 = {0,0,0,0};
        #pragma unroll
        for (int kk = 0; kk < 16; ++kk) {
            f16x8 b  = *(const f16x8*)&zb[kk * 32 + q * 8];
            f16x8 v2 = *(const f16x8*)&m2[kk * 32 + q * 8];
            f16x8 v3 = *(const f16x8*)&m3[kk * 32 + q * 8];
            acc0 = MF(a0[kk], b, acc0);
            acc1 = MF(a1[kk], b, acc1);
            acc2 = MF(v2,     b, acc2);
            acc3 = MF(v3,     b, acc3);
        }
        #pragma unroll
        for (int r4 = 0; r4 < 4; ++r4) {
            Y[0][r4] += acc0[r4] * (1.f / 256.f);
            Y[1][r4] += acc1[r4] * (1.f / 256.f);
            Y[2][r4] += acc2[r4] * (1.f / 256.f);
            Y[3][r4] += acc3[r4] * (1.f / 256.f);
        }
        if (t < 15) {
            _Float16* zn = &Z[(t + 1) & 1][nI * ZROW];
            #pragma unroll
            for (int T = 0; T < 4; ++T) {
                f16x4 zv;
                #pragma unroll
                for (int r4 = 0; r4 < 4; ++r4)
                    zv[r4] = (_Float16)(xn[T][r4] - Y[T][r4]);
                *(f16x4*)&zn[rowbase + T * 16 + q * 4] = zv;
            }
            if (t < 14) {
                const size_t bn = ((size_t)(jt * 128 + tg0 + t + 2) * 512) * 64 + f;
                #pragma unroll
                for (int T = 0; T < 4; ++T)
                    #pragma unroll
                    for (int r4 = 0; r4 < 4; ++r4)
                        xn[T][r4] = xs[bn + (size_t)(rowbase + T * 16 + q * 4 + r4) * 64];
            }
            __syncthreads();
        }
    }

    _Float16* st = state + ((size_t)(ch * 8 + jt) * 64 + f) * 512;
    #pragma unroll
    for (int T = 0; T < 4; ++T) {
        f16x4 sv;
        #pragma unroll
        for (int r4 = 0; r4 < 4; ++r4) sv[r4] = (_Float16)Y[T][r4];
        *(unsigned long long*)&st[rowbase + T * 16 + q * 4] = pack4(sv);
    }
}

// ---------------------------------------------------------------------------
// K7: carry update for chunk cch: state[cch] += G16 @ state[cch-1]  (in place).
// 32 blocks x 512 threads: bx = jt*4 + cg.
// ---------------------------------------------------------------------------
__launch_bounds__(512)
__global__ void k_carry(unsigned char* __restrict__ wsb, int cch)
{
    const _Float16* G16h = (const _Float16*)(wsb + OFF_G0);           // rm hi (256*G16)
    const _Float16* G16l = (const _Float16*)(wsb + OFF_G0) + GSUB;    // rm lo
    _Float16* state = (_Float16*)(wsb + OFF_STATE);

    const int tid = threadIdx.x;
    const int lane = tid & 63, wv = tid >> 6, q = lane >> 4, nI = lane & 15;
    const int bx = blockIdx.x;
    const int jt = bx >> 2, cg = bx & 3;
    const int rowbase = wv * 64;
    const int f = cg * 16 + nI;

    const _Float16* yprev = state + ((size_t)((cch - 1) * 8 + jt) * 64 + f) * 512;
    _Float16*       ycur  = state + ((size_t)(cch * 8 + jt) * 64 + f) * 512;

    f32x4 acc[4] = {{0,0,0,0},{0,0,0,0},{0,0,0,0},{0,0,0,0}};
    #pragma unroll 4
    for (int kk = 0; kk < 16; ++kk) {
        f16x8 b = *(const f16x8*)&yprev[kk * 32 + q * 8];
        #pragma unroll
        for (int T = 0; T < 4; ++T) {
            f16x8 ah = *(const f16x8*)&G16h[(size_t)(rowbase + T * 16 + nI) * 512 + kk * 32 + q * 8];
            f16x8 al = *(const f16x8*)&G16l[(size_t)(rowbase + T * 16 + nI) * 512 + kk * 32 + q * 8];
            acc[T] = MF(ah, b, acc[T]);
            acc[T] = MF(al, b, acc[T]);
        }
    }
    #pragma unroll
    for (int T = 0; T < 4; ++T) {
        f16x4 e4 = *(f16x4*)&ycur[rowbase + T * 16 + q * 4];
        f16x4 nv;
        #pragma unroll
        for (int r4 = 0; r4 < 4; ++r4)
            nv[r4] = (_Float16)((float)e4[r4] + acc[T][r4] * (1.f / 256.f));
        *(unsigned long long*)&ycur[rowbase + T * 16 + q * 4] = pack4(nv);
    }
}

// ---------------------------------------------------------------------------
// K8: phase-2 final chunk scan with carry-in; writes out.
// ---------------------------------------------------------------------------
__launch_bounds__(512, 2)
__global__ void k_phase2(const float* __restrict__ xs, unsigned char* __restrict__ wsb,
                         float* __restrict__ out)
{
    const _Float16* Mrm = (const _Float16*)(wsb + OFF_XRM1);
    const _Float16* state = (const _Float16*)(wsb + OFF_STATE);

    const int tid = threadIdx.x;
    const int lane = tid & 63, wv = tid >> 6, q = lane >> 4, nI = lane & 15;
    const int bx = blockIdx.x;
    const int ch = bx >> 5, jt = (bx >> 2) & 7, cg = bx & 3;
    const int rowbase = wv * 64;
    const int f = cg * 16 + nI;

    __shared__ _Float16 Z[2][16 * ZROW];

    f16x8 a0[16], a1[16];
    #pragma unroll
    for (int kk = 0; kk < 16; ++kk)
        a0[kk] = *(const f16x8*)&Mrm[(size_t)(rowbase + nI) * 512 + kk * 32 + q * 8];
    #pragma unroll
    for (int kk = 0; kk < 16; ++kk)
        a1[kk] = *(const f16x8*)&Mrm[(size_t)(rowbase + 16 + nI) * 512 + kk * 32 + q * 8];
    const _Float16* m2 = &Mrm[(size_t)(rowbase + 32 + nI) * 512];
    const _Float16* m3 = &Mrm[(size_t)(rowbase + 48 + nI) * 512];

    f32x4 Y[4];
    if (ch == 0) {
        #pragma unroll
        for (int T = 0; T < 4; ++T)
            #pragma unroll
            for (int r4 = 0; r4 < 4; ++r4) Y[T][r4] = 0.f;
    } else {
        const _Float16* st = state + ((size_t)((ch - 1) * 8 + jt) * 64 + f) * 512;
        #pragma unroll
        for (int T = 0; T < 4; ++T) {
            f16x4 sv = *(const f16x4*)&st[rowbase + T * 16 + q * 4];
            #pragma unroll
            for (int r4 = 0; r4 < 4; ++r4) Y[T][r4] = (float)sv[r4];
        }
    }

    float xn[4][4];
    const int tg0 = ch * 16;
    {
        const size_t b0 = ((size_t)(jt * 128 + tg0) * 512) * 64 + f;
        #pragma unroll
        for (int T = 0; T < 4; ++T) {
            f16x4 zv;
            #pragma unroll
            for (int r4 = 0; r4 < 4; ++r4) {
                float xv = xs[b0 + (size_t)(rowbase + T * 16 + q * 4 + r4) * 64];
                zv[r4] = (_Float16)(xv - Y[T][r4]);
            }
            *(f16x4*)&Z[0][nI * ZROW + rowbase + T * 16 + q * 4] = zv;
        }
        const size_t b1 = ((size_t)(jt * 128 + tg0 + 1) * 512) * 64 + f;
        #pragma unroll
        for (int T = 0; T < 4; ++T)
            #pragma unroll
            for (int r4 = 0; r4 < 4; ++r4)
                xn[T][r4] = xs[b1 + (size_t)(rowbase + T * 16 + q * 4 + r4) * 64];
    }
    __syncthreads();

    for (int t = 0; t < 16; ++t) {
        const _Float16* zb = &Z[t & 1][nI * ZROW];
        f32x4 acc0 = {0,0,0,0}, acc1 = {0,0,0,0}, acc2 = {0,0,0,0}, acc3 = {0,0,0,0};
        #pragma unroll
        for (int kk = 0; kk < 16; ++kk) {
            f16x8 b  = *(const f16x8*)&zb[kk * 32 + q * 8];
            f16x8 v2 = *(const f16x8*)&m2[kk * 32 + q * 8];
            f16x8 v3 = *(const f16x8*)&m3[kk * 32 + q * 8];
            acc0 = MF(a0[kk], b, acc0);
            acc1 = MF(a1[kk], b, acc1);
            acc2 = MF(v2,     b, acc2);
            acc3 = MF(v3,     b, acc3);
        }
        const size_t base = ((size_t)(jt * 128 + tg0 + t) * 512) * 64 + f;
        #pragma unroll
        for (int r4 = 0; r4 < 4; ++r4) {
            Y[0][r4] += acc0[r4] * (1.f / 256.f);
            Y[1][r4] += acc1[r4] * (1.f / 256.f);
            Y[2][r4] += acc2[r4] * (1.f / 256.f);
            Y[3][r4] += acc3[r4] * (1.f / 256.f);
        }
        #pragma unroll
        for (int T = 0; T < 4; ++T)
            #pragma unroll
            for (int r4 = 0; r4 < 4; ++r4)
                out[base + (size_t)(rowbase + T * 16 + q * 4 + r4) * 64] = Y[T][r4];

        if (t < 15) {
            _Float16* zn = &Z[(t + 1) & 1][nI * ZROW];
            #pragma unroll
            for (int T = 0; T < 4; ++T) {
                f16x4 zv;
                #pragma unroll
                for (int r4 = 0; r4 < 4; ++r4)
                    zv[r4] = (_Float16)(xn[T][r4] - Y[T][r4]);
                *(f16x4*)&zn[rowbase + T * 16 + q * 4] = zv;
            }
            if (t < 14) {
                const size_t bn = ((size_t)(jt * 128 + tg0 + t + 2) * 512) * 64 + f;
                #pragma unroll
                for (int T = 0; T < 4; ++T)
                    #pragma unroll
                    for (int r4 = 0; r4 < 4; ++r4)
                        xn[T][r4] = xs[bn + (size_t)(rowbase + T * 16 + q * 4 + r4) * 64];
            }
            __syncthreads();
        }
    }
}

extern "C" void kernel_launch(void* const* d_in, const int* in_sizes, int n_in,
                              void* d_out, int out_size, void* d_ws, size_t ws_size,
                              hipStream_t stream)
{
    const float* xs = (const float*)d_in[0];   // [8,128,512,64] fp32
    const float* A  = (const float*)d_in[1];   // [1,512,512] fp32
    float* out = (float*)d_out;                // [8,128,512,64] fp32
    unsigned char* ws = (unsigned char*)d_ws;  // ~12.6 MB used

    k_prep_rows<<<dim3(32), dim3(256), 0, stream>>>(A, ws);
    k_init_x<<<dim3(32), dim3(256), 0, stream>>>(ws);

    for (int nit = 0; nit < NITER; ++nit) {
        k_newton_e<<<dim3(256), dim3(256), 0, stream>>>(ws, nit);
        k_newton_u<<<dim3(256), dim3(256), 0, stream>>>(ws, nit);
    }

    k_gprep<<<dim3(32), dim3(256), 0, stream>>>(ws);
    _Float16* G0 = (_Float16*)(ws + OFF_G0);
    _Float16* G1 = (_Float16*)(ws + OFF_G1);
    k_gsq<<<dim3(256), dim3(256), 0, stream>>>(G0, G1);   // G^2
    k_gsq<<<dim3(256), dim3(256), 0, stream>>>(G1, G0);   // G^4
    k_gsq<<<dim3(256), dim3(256), 0, stream>>>(G0, G1);   // G^8
    k_gsq<<<dim3(256), dim3(256), 0, stream>>>(G1, G0);   // G^16 -> buf0

    k_phase1<<<dim3(256), dim3(512), 0, stream>>>(xs, ws);
    for (int c = 1; c < 8; ++c)
        k_carry<<<dim3(32), dim3(512), 0, stream>>>(ws, c);
    k_phase2<<<dim3(256), dim3(512), 0, stream>>>(xs, ws, out);
}